// Round 22
// baseline (559.722 us; speedup 1.0000x reference)
//
#include <hip/hip_runtime.h>
#include <cstdint>

#define ROTL32(v,n) (((v) << (n)) | ((v) >> (32 - (n))))

// ---- JAX threefry-2x32, host version ----
__host__ __forceinline__ void tf2x32(uint32_t k0, uint32_t k1,
                                     uint32_t x0, uint32_t x1,
                                     uint32_t& o0, uint32_t& o1)
{
  uint32_t k2 = k0 ^ k1 ^ 0x1BD11BDAu;
  x0 += k0; x1 += k1;
#define TF_RND(r) { x0 += x1; x1 = ROTL32(x1, (r)); x1 ^= x0; }
  TF_RND(13) TF_RND(15) TF_RND(26) TF_RND(6)
  x0 += k1; x1 += k2 + 1u;
  TF_RND(17) TF_RND(29) TF_RND(16) TF_RND(24)
  x0 += k2; x1 += k0 + 2u;
  TF_RND(13) TF_RND(15) TF_RND(26) TF_RND(6)
  x0 += k0; x1 += k1 + 3u;
  TF_RND(17) TF_RND(29) TF_RND(16) TF_RND(24)
  x0 += k1; x1 += k2 + 4u;
  TF_RND(13) TF_RND(15) TF_RND(26) TF_RND(6)
  x0 += k2; x1 += k0 + 5u;
#undef TF_RND
  o0 = x0; o1 = x1;
}

// ---- device threefry: rotateleft -> v_alignbit_b32 ----
__device__ __forceinline__ void tf2x32_d(uint32_t k0, uint32_t k1,
                                         uint32_t x0, uint32_t x1,
                                         uint32_t& o0, uint32_t& o1)
{
  uint32_t k2 = k0 ^ k1 ^ 0x1BD11BDAu;
  x0 += k0; x1 += k1;
#define R_(r) { x0 += x1; x1 = __builtin_rotateleft32(x1, (r)); x1 ^= x0; }
  R_(13) R_(15) R_(26) R_(6)
  x0 += k1; x1 += k2 + 1u;
  R_(17) R_(29) R_(16) R_(24)
  x0 += k2; x1 += k0 + 2u;
  R_(13) R_(15) R_(26) R_(6)
  x0 += k0; x1 += k1 + 3u;
  R_(17) R_(29) R_(16) R_(24)
  x0 += k1; x1 += k2 + 4u;
  R_(13) R_(15) R_(26) R_(6)
  x0 += k2; x1 += k0 + 5u;
#undef R_
  o0 = x0; o1 = x1;
}

typedef __attribute__((ext_vector_type(8))) _Float16 h16x8;
typedef __attribute__((ext_vector_type(4))) float fl32x4;
typedef __attribute__((ext_vector_type(2))) unsigned long long u64x2;

__device__ __forceinline__ float u2unit_f(uint32_t b) {
  uint32_t r = (b >> 9) | 0x3F800000u;
  float f; __builtin_memcpy(&f, &r, 4); return f - 1.0f;
}

// async global->LDS, 16B per lane; LDS dest = wave-uniform base + lane*16 (m104)
#define GLD16(gp, lp) \
  __builtin_amdgcn_global_load_lds( \
      (__attribute__((address_space(1))) void*)(gp), \
      (__attribute__((address_space(3))) void*)(lp), 16, 0, 0)

#define VMW(n) asm volatile("s_waitcnt vmcnt(" #n ")" ::: "memory")
#define LKW0() asm volatile("s_waitcnt lgkmcnt(0)" ::: "memory")
#define SBAR() asm volatile("s_barrier" ::: "memory")

// ---- x convert + pad (65536,784)f32 -> (65536,832)fp16, + mL0 words [0,319488) ----
__global__ __launch_bounds__(256) void cvt_x_f(const float* __restrict__ x,
                                               _Float16* __restrict__ xp,
                                               unsigned long long* __restrict__ m0,
                                               uint32_t k0, uint32_t k1)
{
  int idx = blockIdx.x * 256 + threadIdx.x;   // 65536*104 chunks of 8
  int row = idx / 104, c = idx - row * 104;
  h16x8 o = {0,0,0,0,0,0,0,0};
  if (c < 98) {
    const fl32x4* p = (const fl32x4*)&x[row * 784 + c * 8];
    fl32x4 a = p[0], b = p[1];
    o[0] = (_Float16)a[0]; o[1] = (_Float16)a[1]; o[2] = (_Float16)a[2]; o[3] = (_Float16)a[3];
    o[4] = (_Float16)b[0]; o[5] = (_Float16)b[1]; o[6] = (_Float16)b[2]; o[7] = (_Float16)b[3];
  }
  *(h16x8*)&xp[row * 832 + c * 8] = o;

  // L0 masks, 3 words/wave: 106496 waves * 3 = 319488 words exactly
  uint32_t lane = threadIdx.x & 63u;
  uint32_t gw = (uint32_t)blockIdx.x * 4u + ((uint32_t)threadIdx.x >> 6);
#pragma unroll
  for (int i = 0; i < 3; ++i) {
    uint32_t wix = gw * 3u + (uint32_t)i;     // < 319488 always
    uint32_t b1, b2;
    tf2x32_d(k0, k1, 0u, wix * 64u + lane, b1, b2);
    unsigned long long mw = __ballot(u2unit_f(b1 ^ b2) < 0.8f);
    if (lane == 0) m0[wix] = mw;
  }
}

// ---- weight transpose+convert (W1 padded) + mL0 words [319488, 524288) ----
__global__ __launch_bounds__(256) void cvt_w_f(
    const float* __restrict__ W1, const float* __restrict__ W2, const float* __restrict__ W3,
    const float* __restrict__ W4, const float* __restrict__ W5, const float* __restrict__ W6,
    const float* __restrict__ W7, _Float16* __restrict__ WT1, _Float16* __restrict__ WT,
    unsigned long long* __restrict__ m0, uint32_t k0, uint32_t k1)
{
  int b = blockIdx.x;
  if (b < 1666) {                              // 512*832 = 426496 elems
    int idx = b * 256 + threadIdx.x;           // n*832 + k
    int n = idx / 832, k = idx - n * 832;
    WT1[idx] = (k < 784) ? (_Float16)W1[k * 512 + n] : (_Float16)0.f;
  } else {                                     // 6 layers of 512*512
    int l = (b - 1666) >> 10;
    int idx = ((b - 1666) & 1023) * 256 + threadIdx.x;
    int n = idx >> 9, k = idx & 511;
    const float* Wp = (l == 0) ? W2 : (l == 1) ? W3 : (l == 2) ? W4
                    : (l == 3) ? W5 : (l == 4) ? W6 : W7;
    WT[l * 262144 + idx] = (_Float16)Wp[k * 512 + n];
  }
  // L0 masks, 7 words/wave: 31240 waves cover [319488, 524288) with guard
  uint32_t lane = threadIdx.x & 63u;
  uint32_t gw = (uint32_t)blockIdx.x * 4u + ((uint32_t)threadIdx.x >> 6);
#pragma unroll
  for (int i = 0; i < 7; ++i) {
    uint32_t wix = 319488u + gw * 7u + (uint32_t)i;
    if (wix < 524288u) {                       // wave-uniform guard
      uint32_t b1, b2;
      tf2x32_d(k0, k1, 0u, wix * 64u + lane, b1, b2);
      unsigned long long mw = __ballot(u2unit_f(b1 ^ b2) < 0.8f);
      if (lane == 0) m0[wix] = mw;
    }
  }
}

// ---- GEMM: 128x256 tile (BN=256 halves A re-reads), BK=32, 512 thr / 8 waves. ----
// Wave (wr=wv>>2 in 0..1, wc=wv&3 in 0..3): 64x64 quadrant = 4x4 frags (r19's).
// k-loop: r19 structure (running pointers, 2-slot dbuf, counted vmcnt(3),
// 2 barriers/step). Per-wave flush epilogue + shuffle-free fused head.
template<bool DROP, bool HEAD>
__global__ __launch_bounds__(512, 4) void gemm_r(
    const _Float16* __restrict__ A, const _Float16* __restrict__ BT,
    const float* __restrict__ bias, const unsigned long long* __restrict__ mask,
    float invq, _Float16* __restrict__ C, int K,
    unsigned long long* __restrict__ mout, uint32_t mbase, int tfcap,
    uint32_t mk0, uint32_t mk1, float mq,
    const float* __restrict__ W8g, float* __restrict__ plog)
{
  __shared__ __align__(16) _Float16 sm[24576];   // 49152 B: 2 slots x (A 4096 + B 8192)
  const int tid  = threadIdx.x;
  const int lane = tid & 63;
  const int wv   = tid >> 6;
  const int wr   = wv >> 2, wc = wv & 3;
  const int rml  = lane & 15;
  const int kq   = lane >> 4;

  // bijective XCD swizzle: 1024 blocks = 8 x 128; consecutive t share the A panel
  int bid = blockIdx.x;
  int t = (bid & 7) * 128 + (bid >> 3);
  int bm = (t >> 1) * 128;
  int bn = (t & 1) * 256;

  // staging (r9 swizzle, per-pair-row relation): A chunk id = tid (512 chunks),
  // B chunk ids = {tid, 512+tid} (1024 chunks; same sin since (g*64)&7 == 0).
  const int sp   = tid >> 3;                   // pair-row 0..63
  const int sin  = (tid & 7) ^ (sp & 7);
  const int srow = 2 * sp + (sin >> 2);        // 0..127
  const int sk16 = sin & 3;

  // running source pointers (ONE add each per step)
  const _Float16* pA0 = A  + (size_t)(bm + srow)       * K + sk16 * 8;
  const _Float16* pB0 = BT + (size_t)(bn + srow)       * K + sk16 * 8;
  const _Float16* pB1 = BT + (size_t)(bn + srow + 128) * K + sk16 * 8;

  // read constants (r9): slot16 = ((rml&1)<<2 | kq) ^ (rml>>1)
  const int rslot = (((rml & 1) << 2) | kq) ^ (rml >> 1);
  const int abase = (wr * 32 + (rml >> 1)) * 64 + rslot * 8;
  const int bbase = 4096 + (wc * 32 + (rml >> 1)) * 64 + rslot * 8;

  fl32x4 acc[4][4];
#pragma unroll
  for (int i = 0; i < 4; ++i)
#pragma unroll
    for (int j = 0; j < 4; ++j)
      acc[i][j] = (fl32x4){0.f, 0.f, 0.f, 0.f};

  const int nst = K >> 5;

#define STAGEP(selem) do {                                                     \
    GLD16(pA0, sm + (selem) + wv * 512);                                       \
    GLD16(pB0, sm + (selem) + 4096 + wv * 512);                                \
    GLD16(pB1, sm + (selem) + 8192 + wv * 512);                                \
  } while (0)
#define ADVP() do { pA0 += 32; pB0 += 32; pB1 += 32; } while (0)

  STAGEP(0);                                   // tile 0 -> slot 0
  ADVP();                                      // pointers -> tile 1

  uint64_t mw0 = 0;
  int tfc = 0;
  uint32_t gw = (uint32_t)bid * 8u + (uint32_t)wv;   // 8192 waves total
  uint32_t xrun = (mbase + gw * (uint32_t)tfcap) * 64u + (uint32_t)lane;

#pragma unroll 1
  for (int kt = 0; kt < nst; ++kt) {
    const int slot = (kt & 1) * 12288;
    if (kt + 1 < nst) { STAGEP(12288 - slot); ADVP(); }
    // hosted threefry mask words (register-held; statically unrolled x2)
    if (mout != nullptr && tfc < tfcap) {
#pragma unroll
      for (int i_ = 0; i_ < 2; ++i_) {
        uint32_t a_, b_;
        tf2x32_d(mk0, mk1, 0u, xrun, a_, b_);
        unsigned long long bal = __ballot(u2unit_f(a_ ^ b_) < mq);
        if (lane == tfc) mw0 = bal;
        ++tfc; xrun += 64u;
      }
    }
    if (kt + 1 < nst) { VMW(3); } else { VMW(0); }   // counted: own 3 stay in flight
    SBAR();
    h16x8 af[4], bf[4];
#pragma unroll
    for (int mf = 0; mf < 4; ++mf)
      af[mf] = *(const h16x8*)&sm[slot + abase + mf * 512];
#pragma unroll
    for (int nf = 0; nf < 4; ++nf)
      bf[nf] = *(const h16x8*)&sm[slot + bbase + nf * 512];
#pragma unroll
    for (int mf = 0; mf < 4; ++mf)
#pragma unroll
      for (int nf = 0; nf < 4; ++nf)
        acc[mf][nf] = __builtin_amdgcn_mfma_f32_16x16x32_f16(af[mf], bf[nf], acc[mf][nf], 0, 0, 0);
    SBAR();                                    // guards 2-slot reuse next step
  }
#undef STAGEP
#undef ADVP

  // mask words out (LINEAR layout), one coalesced store per wave
  if (mout != nullptr && lane < tfcap)
    mout[mbase + gw * (uint32_t)tfcap + (uint32_t)lane] = mw0;

  const int eb = wv * 2176;                    // 32 rows x 68 elems per wave (max 17403)
  const int lrr = lane >> 1;                   // row 0..31 (2 lanes per row)

  if (HEAD) {
    // ---- fused head, shuffle-free: fp16 quadrant -> LDS -> per-row dot ----
    // W8 slice (256 cols x 10 fp32 = 10240 B) at elems [17408, 22528).
    float* W8l = (float*)(sm + 17408);
    for (int i = tid; i < 2560; i += 512) {
      int k = i / 10, c = i - k * 10;
      W8l[i] = W8g[(size_t)(bn + k) * 10 + c];
    }
    __syncthreads();
    float* pout = plog + (size_t)((t & 1) * 4 + wc) * 655360;
    const int ch = lane & 1;                   // column half 0/1 (32 cols each)

#define HEPI(HALF) do {                                                        \
    _Pragma("unroll")                                                          \
    for (int nf = 0; nf < 4; ++nf) {                                           \
      int colq = nf * 16 + rml;                                                \
      float bv = bias[bn + wc * 64 + colq];                                    \
      _Pragma("unroll")                                                        \
      for (int mfh = 0; mfh < 2; ++mfh) {                                      \
        _Pragma("unroll")                                                      \
        for (int r = 0; r < 4; ++r) {                                          \
          int lr = mfh * 16 + kq * 4 + r;                                      \
          float v = fmaxf(acc[(HALF) * 2 + mfh][nf][r] + bv, 0.0f);            \
          sm[eb + lr * 68 + colq] = (_Float16)v;                               \
        }                                                                      \
      }                                                                        \
    }                                                                          \
    LKW0();                                                                    \
    {                                                                          \
      float p[10];                                                             \
      _Pragma("unroll")                                                        \
      for (int c = 0; c < 10; ++c) p[c] = 0.f;                                 \
      _Pragma("unroll")                                                        \
      for (int j = 0; j < 4; ++j) {                                            \
        h16x8 hv = *(const h16x8*)&sm[eb + lrr * 68 + ch * 32 + j * 8];        \
        _Pragma("unroll")                                                      \
        for (int e = 0; e < 8; ++e) {                                          \
          float hf = (float)hv[e];                                             \
          const float* wrow = &W8l[(wc * 64 + ch * 32 + j * 8 + e) * 10];      \
          _Pragma("unroll")                                                    \
          for (int c = 0; c < 10; ++c) p[c] += hf * wrow[c];                   \
        }                                                                      \
      }                                                                        \
      _Pragma("unroll")                                                        \
      for (int c = 0; c < 10; ++c) p[c] += __shfl_xor(p[c], 1);                \
      if (ch == 0) {                                                           \
        int row = bm + wr * 64 + (HALF) * 32 + lrr;                            \
        _Pragma("unroll")                                                      \
        for (int c = 0; c < 10; ++c) pout[(size_t)row * 10 + c] = p[c];        \
      }                                                                        \
    }                                                                          \
  } while (0)

    HEPI(0);
    HEPI(1);
#undef HEPI
    return;
  }

  // ---- epilogue: two wave-private half-passes, HALF is a LITERAL (rule #20) ----
  const int cbase = (lane & 1) * 4;            // chunk group 0..3 / 4..7

#define EPIHALF(HALF) do {                                                     \
    _Pragma("unroll")                                                          \
    for (int nf = 0; nf < 4; ++nf) {                                           \
      int colq = nf * 16 + rml;                                                \
      float bv = bias[bn + wc * 64 + colq];                                    \
      _Pragma("unroll")                                                        \
      for (int mfh = 0; mfh < 2; ++mfh) {                                      \
        _Pragma("unroll")                                                      \
        for (int r = 0; r < 4; ++r) {                                          \
          int lr = mfh * 16 + kq * 4 + r;                                      \
          float v = fmaxf(acc[(HALF) * 2 + mfh][nf][r] + bv, 0.0f) * invq;     \
          sm[eb + lr * 68 + colq] = (_Float16)v;                               \
        }                                                                      \
      }                                                                        \
    }                                                                          \
    LKW0();                                                                    \
    {                                                                          \
      int grow = bm + wr * 64 + (HALF) * 32 + lrr;                             \
      int col0 = bn + wc * 64;                                                 \
      uint64_t mw = 0;                                                         \
      if (DROP) mw = mask[(size_t)grow * 8 + (size_t)(col0 >> 6)];             \
      _Pragma("unroll")                                                        \
      for (int c = 0; c < 4; ++c) {                                            \
        int cc = cbase + c;                                                    \
        uint64_t lo = *(const uint64_t*)&sm[eb + lrr * 68 + cc * 8];           \
        uint64_t hi = *(const uint64_t*)&sm[eb + lrr * 68 + cc * 8 + 4];       \
        if (DROP) {                                                            \
          uint32_t bits = (uint32_t)(mw >> (cc * 8)) & 0xffu;                  \
          uint64_t klo = 0, khi = 0;                                           \
          if (bits & 0x01u) klo |= 0x000000000000ffffull;                      \
          if (bits & 0x02u) klo |= 0x00000000ffff0000ull;                      \
          if (bits & 0x04u) klo |= 0x0000ffff00000000ull;                      \
          if (bits & 0x08u) klo |= 0xffff000000000000ull;                      \
          if (bits & 0x10u) khi |= 0x000000000000ffffull;                      \
          if (bits & 0x20u) khi |= 0x00000000ffff0000ull;                      \
          if (bits & 0x40u) khi |= 0x0000ffff00000000ull;                      \
          if (bits & 0x80u) khi |= 0xffff000000000000ull;                      \
          lo &= klo; hi &= khi;                                                \
        }                                                                      \
        u64x2 ov; ov[0] = lo; ov[1] = hi;                                      \
        *(u64x2*)&C[(size_t)grow * 512 + col0 + cc * 8] = ov;                  \
      }                                                                        \
    }                                                                          \
  } while (0)

  EPIHALF(0);
  // same-wave DS ordering sequences half-1 ds_writes after half-0 ds_reads
  EPIHALF(1);
#undef EPIHALF
}

// ---- softmax over summed partial logits: out[row][c] ----
__global__ __launch_bounds__(256) void smax_k(const float* __restrict__ plog,
                                              const float* __restrict__ b8,
                                              float* __restrict__ out)
{
  int row = blockIdx.x * 256 + threadIdx.x;    // 65536 rows
  float l[10];
#pragma unroll
  for (int c = 0; c < 10; ++c) l[c] = b8[c];
#pragma unroll
  for (int s = 0; s < 8; ++s) {
    const float* pr = &plog[(size_t)s * 655360 + (size_t)row * 10];
#pragma unroll
    for (int c = 0; c < 10; ++c) l[c] += pr[c];
  }
  float mx = l[0];
#pragma unroll
  for (int c = 1; c < 10; ++c) mx = fmaxf(mx, l[c]);
  float sum = 0.f, e[10];
#pragma unroll
  for (int c = 0; c < 10; ++c) { e[c] = expf(l[c] - mx); sum += e[c]; }
  float is = 1.0f / sum;
#pragma unroll
  for (int c = 0; c < 10; ++c) out[(size_t)row * 10 + c] = e[c] * is;
}

extern "C" void kernel_launch(void* const* d_in, const int* in_sizes, int n_in,
                              void* d_out, int out_size, void* d_ws, size_t ws_size,
                              hipStream_t stream) {
  (void)in_sizes; (void)n_in; (void)out_size; (void)ws_size;
  const float* x = (const float*)d_in[0];
  const float* W[8]; const float* B[8];
  for (int i = 0; i < 8; ++i) { W[i] = (const float*)d_in[1 + 2*i]; B[i] = (const float*)d_in[2 + 2*i]; }

  char* w = (char*)d_ws;                       // ~260 MB total
  _Float16* xpad = (_Float16*)(w);             // 65536*832 fp16   = 109,051,904 B
  float*    plog = (float*)(w);                // 8 x 655360 f32 = 21 MB (reuses xpad,
                                               // dead after g1; g7 writes, smax reads)
  _Float16* hA   = (_Float16*)(w + 109051904); // 65536*512 fp16   =  67,108,864 B
  _Float16* hB   = (_Float16*)(w + 176160768); // 65536*512 fp16   =  67,108,864 B
  _Float16* WT1  = (_Float16*)(w + 243269632); // 512*832 fp16     =     851,968 B
  _Float16* WT   = (_Float16*)(w + 244121600); // 6 x 512*512 fp16 =   3,145,728 B
  unsigned long long* masks = (unsigned long long*)(w + 247267328); // 3*4 MiB
  unsigned long long* mL0 = masks;
  unsigned long long* mL1 = masks + 524288;
  unsigned long long* mL2 = masks + 1048576;

  // jax.random.split(key(42), 3), threefry_partitionable (foldlike) path:
  // child i = BOTH output words of threefry(key=(0,42), counter=(0,i))
  uint32_t d00,d01,d10,d11,d20,d21;
  tf2x32(0u, 42u, 0u, 0u, d00, d01);           // dk[0]  (p=0.2, q=0.8)
  tf2x32(0u, 42u, 0u, 1u, d10, d11);           // dk[1]  (p=0.3, q=0.7)
  tf2x32(0u, 42u, 0u, 2u, d20, d21);           // dk[2]  (p=0.5, q=0.5)

  cvt_x_f<<<26624, 256, 0, stream>>>(x, xpad, mL0, d00, d01);
  cvt_w_f<<<7810, 256, 0, stream>>>(W[0],W[1],W[2],W[3],W[4],W[5],W[6], WT1, WT,
                                    mL0, d00, d01);

  dim3 g(1024), b(512);
  // hosting: mL0 by cvt_x+cvt_w (used g2); mL1 by g2+g3 (used g4);
  // mL2 by g4+g5 (used g6). 8192 waves x 32 words = 262144 per host kernel.
  gemm_r<false,false><<<g, b, 0, stream>>>(xpad, WT1,           B[0], nullptr, 1.0f,      hA, 832,
                                     nullptr, 0u, 0, 0u, 0u, 0.f, nullptr, nullptr);
  gemm_r<true ,false><<<g, b, 0, stream>>>(hA,   WT + 0*262144, B[1], mL0,     1.0f/0.8f, hB, 512,
                                     mL1, 0u,       32, d10, d11, 0.7f, nullptr, nullptr);
  gemm_r<false,false><<<g, b, 0, stream>>>(hB,   WT + 1*262144, B[2], nullptr, 1.0f,      hA, 512,
                                     mL1, 262144u,  32, d10, d11, 0.7f, nullptr, nullptr);
  gemm_r<true ,false><<<g, b, 0, stream>>>(hA,   WT + 2*262144, B[3], mL1,     1.0f/0.7f, hB, 512,
                                     mL2, 0u,       32, d20, d21, 0.5f, nullptr, nullptr);
  gemm_r<false,false><<<g, b, 0, stream>>>(hB,   WT + 3*262144, B[4], nullptr, 1.0f,      hA, 512,
                                     mL2, 262144u,  32, d20, d21, 0.5f, nullptr, nullptr);
  gemm_r<true ,false><<<g, b, 0, stream>>>(hA,   WT + 4*262144, B[5], mL2,     2.0f,      hB, 512,
                                     nullptr, 0u, 0, 0u, 0u, 0.f, nullptr, nullptr);
  gemm_r<false,true ><<<g, b, 0, stream>>>(hB,   WT + 5*262144, B[6], nullptr, 1.0f,      hA, 512,
                                     nullptr, 0u, 0, 0u, 0u, 0.f, W[7], plog);
  smax_k<<<256, 256, 0, stream>>>(plog, B[7], (float*)d_out);
}

// Round 23
// 549.367 us; speedup vs baseline: 1.0188x; 1.0188x over previous
//
#include <hip/hip_runtime.h>
#include <cstdint>

#define ROTL32(v,n) (((v) << (n)) | ((v) >> (32 - (n))))

// ---- JAX threefry-2x32, host version ----
__host__ __forceinline__ void tf2x32(uint32_t k0, uint32_t k1,
                                     uint32_t x0, uint32_t x1,
                                     uint32_t& o0, uint32_t& o1)
{
  uint32_t k2 = k0 ^ k1 ^ 0x1BD11BDAu;
  x0 += k0; x1 += k1;
#define TF_RND(r) { x0 += x1; x1 = ROTL32(x1, (r)); x1 ^= x0; }
  TF_RND(13) TF_RND(15) TF_RND(26) TF_RND(6)
  x0 += k1; x1 += k2 + 1u;
  TF_RND(17) TF_RND(29) TF_RND(16) TF_RND(24)
  x0 += k2; x1 += k0 + 2u;
  TF_RND(13) TF_RND(15) TF_RND(26) TF_RND(6)
  x0 += k0; x1 += k1 + 3u;
  TF_RND(17) TF_RND(29) TF_RND(16) TF_RND(24)
  x0 += k1; x1 += k2 + 4u;
  TF_RND(13) TF_RND(15) TF_RND(26) TF_RND(6)
  x0 += k2; x1 += k0 + 5u;
#undef TF_RND
  o0 = x0; o1 = x1;
}

// ---- device threefry: rotateleft -> v_alignbit_b32 ----
__device__ __forceinline__ void tf2x32_d(uint32_t k0, uint32_t k1,
                                         uint32_t x0, uint32_t x1,
                                         uint32_t& o0, uint32_t& o1)
{
  uint32_t k2 = k0 ^ k1 ^ 0x1BD11BDAu;
  x0 += k0; x1 += k1;
#define R_(r) { x0 += x1; x1 = __builtin_rotateleft32(x1, (r)); x1 ^= x0; }
  R_(13) R_(15) R_(26) R_(6)
  x0 += k1; x1 += k2 + 1u;
  R_(17) R_(29) R_(16) R_(24)
  x0 += k2; x1 += k0 + 2u;
  R_(13) R_(15) R_(26) R_(6)
  x0 += k0; x1 += k1 + 3u;
  R_(17) R_(29) R_(16) R_(24)
  x0 += k1; x1 += k2 + 4u;
  R_(13) R_(15) R_(26) R_(6)
  x0 += k2; x1 += k0 + 5u;
#undef R_
  o0 = x0; o1 = x1;
}

typedef __attribute__((ext_vector_type(8))) _Float16 h16x8;
typedef __attribute__((ext_vector_type(4))) float fl32x4;
typedef __attribute__((ext_vector_type(2))) unsigned long long u64x2;

__device__ __forceinline__ float u2unit_f(uint32_t b) {
  uint32_t r = (b >> 9) | 0x3F800000u;
  float f; __builtin_memcpy(&f, &r, 4); return f - 1.0f;
}

// async global->LDS, 16B per lane; LDS dest = wave-uniform base + lane*16 (m104)
#define GLD16(gp, lp) \
  __builtin_amdgcn_global_load_lds( \
      (__attribute__((address_space(1))) void*)(gp), \
      (__attribute__((address_space(3))) void*)(lp), 16, 0, 0)

#define VMW(n) asm volatile("s_waitcnt vmcnt(" #n ")" ::: "memory")
#define LKW0() asm volatile("s_waitcnt lgkmcnt(0)" ::: "memory")
#define SBAR() asm volatile("s_barrier" ::: "memory")

// ---- x convert + pad (65536,784)f32 -> (65536,832)fp16, + mL0 words [0,319488) ----
__global__ __launch_bounds__(256) void cvt_x_f(const float* __restrict__ x,
                                               _Float16* __restrict__ xp,
                                               unsigned long long* __restrict__ m0,
                                               uint32_t k0, uint32_t k1)
{
  int idx = blockIdx.x * 256 + threadIdx.x;   // 65536*104 chunks of 8
  int row = idx / 104, c = idx - row * 104;
  h16x8 o = {0,0,0,0,0,0,0,0};
  if (c < 98) {
    const fl32x4* p = (const fl32x4*)&x[row * 784 + c * 8];
    fl32x4 a = p[0], b = p[1];
    o[0] = (_Float16)a[0]; o[1] = (_Float16)a[1]; o[2] = (_Float16)a[2]; o[3] = (_Float16)a[3];
    o[4] = (_Float16)b[0]; o[5] = (_Float16)b[1]; o[6] = (_Float16)b[2]; o[7] = (_Float16)b[3];
  }
  *(h16x8*)&xp[row * 832 + c * 8] = o;

  // L0 masks, 3 words/wave: 106496 waves * 3 = 319488 words exactly
  uint32_t lane = threadIdx.x & 63u;
  uint32_t gw = (uint32_t)blockIdx.x * 4u + ((uint32_t)threadIdx.x >> 6);
#pragma unroll
  for (int i = 0; i < 3; ++i) {
    uint32_t wix = gw * 3u + (uint32_t)i;     // < 319488 always
    uint32_t b1, b2;
    tf2x32_d(k0, k1, 0u, wix * 64u + lane, b1, b2);
    unsigned long long mw = __ballot(u2unit_f(b1 ^ b2) < 0.8f);
    if (lane == 0) m0[wix] = mw;
  }
}

// ---- weight transpose+convert (W1 padded) + mL0 words [319488, 524288) ----
__global__ __launch_bounds__(256) void cvt_w_f(
    const float* __restrict__ W1, const float* __restrict__ W2, const float* __restrict__ W3,
    const float* __restrict__ W4, const float* __restrict__ W5, const float* __restrict__ W6,
    const float* __restrict__ W7, _Float16* __restrict__ WT1, _Float16* __restrict__ WT,
    unsigned long long* __restrict__ m0, uint32_t k0, uint32_t k1)
{
  int b = blockIdx.x;
  if (b < 1666) {                              // 512*832 = 426496 elems
    int idx = b * 256 + threadIdx.x;           // n*832 + k
    int n = idx / 832, k = idx - n * 832;
    WT1[idx] = (k < 784) ? (_Float16)W1[k * 512 + n] : (_Float16)0.f;
  } else {                                     // 6 layers of 512*512
    int l = (b - 1666) >> 10;
    int idx = ((b - 1666) & 1023) * 256 + threadIdx.x;
    int n = idx >> 9, k = idx & 511;
    const float* Wp = (l == 0) ? W2 : (l == 1) ? W3 : (l == 2) ? W4
                    : (l == 3) ? W5 : (l == 4) ? W6 : W7;
    WT[l * 262144 + idx] = (_Float16)Wp[k * 512 + n];
  }
  // L0 masks, 7 words/wave: 31240 waves cover [319488, 524288) with guard
  uint32_t lane = threadIdx.x & 63u;
  uint32_t gw = (uint32_t)blockIdx.x * 4u + ((uint32_t)threadIdx.x >> 6);
#pragma unroll
  for (int i = 0; i < 7; ++i) {
    uint32_t wix = 319488u + gw * 7u + (uint32_t)i;
    if (wix < 524288u) {                       // wave-uniform guard
      uint32_t b1, b2;
      tf2x32_d(k0, k1, 0u, wix * 64u + lane, b1, b2);
      unsigned long long mw = __ballot(u2unit_f(b1 ^ b2) < 0.8f);
      if (lane == 0) m0[wix] = mw;
    }
  }
}

// ---- GEMM: 128x128 tile, BK=32, 256 thr / 4 waves, 2-slot dbuf, vmcnt(4). ----
// k-loop: r21 structure DOUBLED (static slot constants, no per-step slot calc
// or stage conditionals -- VALU/SALU issue is the measured binding resource).
// HEAD=true: fused head via LDS round-trip (shuffle-free).
template<bool DROP, bool HEAD>
__global__ __launch_bounds__(256, 4) void gemm_r(
    const _Float16* __restrict__ A, const _Float16* __restrict__ BT,
    const float* __restrict__ bias, const unsigned long long* __restrict__ mask,
    float invq, _Float16* __restrict__ C, int K,
    unsigned long long* __restrict__ mout, uint32_t mbase, int tfcap,
    uint32_t mk0, uint32_t mk1, float mq,
    const float* __restrict__ W8g, float* __restrict__ plog)
{
  __shared__ __align__(16) _Float16 sm[16384];   // 32768 B: 2 slots x (A 4096 + B 4096)
  const int tid  = threadIdx.x;
  const int lane = tid & 63;
  const int wv   = tid >> 6;
  const int wr   = wv >> 1, wc = wv & 1;
  const int rml  = lane & 15;
  const int kq   = lane >> 4;

  // bijective XCD swizzle: 2048 blocks = 8 x 256; consecutive t share the A panel
  int bid = blockIdx.x;
  int t = (bid & 7) * 256 + (bid >> 3);
  int bm = (t >> 2) * 128;
  int bn = (t & 3) * 128;

  // staging constants (r9 swizzle): thread -> A chunks {tid, 256+tid}, B same
  const int sp   = tid >> 3;                   // pair-row 0..31
  const int sin  = (tid & 7) ^ (sp & 7);
  const int srow = 2 * sp + (sin >> 2);        // 0..63 (group0); +64 group1
  const int sk16 = sin & 3;

  // running source pointers (ONE add each per step -- no per-step recompute)
  const _Float16* pA0 = A  + (size_t)(bm + srow)      * K + sk16 * 8;
  const _Float16* pA1 = A  + (size_t)(bm + srow + 64) * K + sk16 * 8;
  const _Float16* pB0 = BT + (size_t)(bn + srow)      * K + sk16 * 8;
  const _Float16* pB1 = BT + (size_t)(bn + srow + 64) * K + sk16 * 8;

  // read constants (r9): slot16 = ((rml&1)<<2 | kq) ^ (rml>>1)
  const int rslot = (((rml & 1) << 2) | kq) ^ (rml >> 1);
  const int abase = (wr * 32 + (rml >> 1)) * 64 + rslot * 8;
  const int bbase = 4096 + (wc * 32 + (rml >> 1)) * 64 + rslot * 8;

  fl32x4 acc[4][4];
#pragma unroll
  for (int i = 0; i < 4; ++i)
#pragma unroll
    for (int j = 0; j < 4; ++j)
      acc[i][j] = (fl32x4){0.f, 0.f, 0.f, 0.f};

  const int nst = K >> 5;                      // 26 or 16 (always even)
  const int nd  = nst >> 1;

#define STAGEP(selem) do {                                                     \
    GLD16(pA0, sm + (selem) + wv * 512);                                       \
    GLD16(pA1, sm + (selem) + 2048 + wv * 512);                                \
    GLD16(pB0, sm + (selem) + 4096 + wv * 512);                                \
    GLD16(pB1, sm + (selem) + 6144 + wv * 512);                                \
  } while (0)
#define ADVP() do { pA0 += 32; pA1 += 32; pB0 += 32; pB1 += 32; } while (0)

#define HOST2() do {                                                           \
    if (mout != nullptr && tfc < tfcap) {                                      \
      _Pragma("unroll")                                                        \
      for (int i_ = 0; i_ < 2; ++i_) {                                         \
        uint32_t a_, b_;                                                       \
        tf2x32_d(mk0, mk1, 0u, xrun, a_, b_);                                  \
        unsigned long long bal = __ballot(u2unit_f(a_ ^ b_) < mq);             \
        if (lane == tfc) mw0 = bal;                                            \
        ++tfc; xrun += 64u;                                                    \
      }                                                                        \
    } } while (0)

#define COMPUTE(selem) do {                                                    \
    h16x8 af[4], bf[4];                                                        \
    _Pragma("unroll")                                                          \
    for (int mf = 0; mf < 4; ++mf)                                             \
      af[mf] = *(const h16x8*)&sm[(selem) + abase + mf * 512];                 \
    _Pragma("unroll")                                                          \
    for (int nf = 0; nf < 4; ++nf)                                             \
      bf[nf] = *(const h16x8*)&sm[(selem) + bbase + nf * 512];                 \
    _Pragma("unroll")                                                          \
    for (int mf = 0; mf < 4; ++mf)                                             \
      _Pragma("unroll")                                                        \
      for (int nf = 0; nf < 4; ++nf)                                           \
        acc[mf][nf] = __builtin_amdgcn_mfma_f32_16x16x32_f16(                  \
            af[mf], bf[nf], acc[mf][nf], 0, 0, 0);                             \
  } while (0)

  STAGEP(0);                                   // tile 0 -> slot 0
  ADVP();                                      // pointers -> tile 1

  uint64_t mw0 = 0;
  int tfc = 0;
  uint32_t gw = (uint32_t)bid * 4u + (uint32_t)wv;   // 8192 waves total
  uint32_t xrun = (mbase + gw * (uint32_t)tfcap) * 64u + (uint32_t)lane;

#pragma unroll 1
  for (int it = 0; it < nd - 1; ++it) {
    // step even: compute slot 0, prefetch -> slot 8192
    STAGEP(8192); ADVP();
    HOST2();
    VMW(4); SBAR();
    COMPUTE(0);
    SBAR();
    // step odd: compute slot 8192, prefetch -> slot 0
    STAGEP(0); ADVP();
    HOST2();
    VMW(4); SBAR();
    COMPUTE(8192);
    SBAR();
  }
  // peeled final pair: step nst-2 (stages last tile), step nst-1 (drain)
  STAGEP(8192);
  HOST2();
  VMW(4); SBAR();
  COMPUTE(0);
  SBAR();
  HOST2();
  VMW(0); SBAR();
  COMPUTE(8192);
  SBAR();                                      // all waves past final reads
#undef STAGEP
#undef ADVP
#undef HOST2
#undef COMPUTE

  // mask words out (LINEAR layout), one coalesced store per wave
  if (mout != nullptr && lane < tfcap)
    mout[mbase + gw * (uint32_t)tfcap + (uint32_t)lane] = mw0;

  const int eb = wv * 2176;                    // 32 rows x 68 elems per wave
  const int lrr = lane >> 1;                   // row 0..31 (2 lanes per row)

  if (HEAD) {
    // ---- fused head, shuffle-free: fp16 quadrant -> LDS -> per-row dot ----
    // W8 slice at LDS elems [9216, 11776): disjoint from h regions [0, 8704).
    float* W8l = (float*)(sm + 9216);          // 128 cols x 10 classes fp32
    for (int i = tid; i < 1280; i += 256) {
      int k = i / 10, c = i - k * 10;
      W8l[i] = W8g[(size_t)(bn + k) * 10 + c];
    }
    __syncthreads();
    float* pout = plog + (size_t)((t & 3) * 2 + wc) * 655360;
    const int ch = lane & 1;                   // column half 0/1 (32 cols each)

#define HEPI(HALF) do {                                                        \
    _Pragma("unroll")                                                          \
    for (int nf = 0; nf < 4; ++nf) {                                           \
      int colq = nf * 16 + rml;                                                \
      float bv = bias[bn + wc * 64 + colq];                                    \
      _Pragma("unroll")                                                        \
      for (int mfh = 0; mfh < 2; ++mfh) {                                      \
        _Pragma("unroll")                                                      \
        for (int r = 0; r < 4; ++r) {                                          \
          int lr = mfh * 16 + kq * 4 + r;                                      \
          float v = fmaxf(acc[(HALF) * 2 + mfh][nf][r] + bv, 0.0f);            \
          sm[eb + lr * 68 + colq] = (_Float16)v;                               \
        }                                                                      \
      }                                                                        \
    }                                                                          \
    LKW0();                                                                    \
    {                                                                          \
      float p[10];                                                             \
      _Pragma("unroll")                                                        \
      for (int c = 0; c < 10; ++c) p[c] = 0.f;                                 \
      _Pragma("unroll")                                                        \
      for (int j = 0; j < 4; ++j) {                                            \
        h16x8 hv = *(const h16x8*)&sm[eb + lrr * 68 + ch * 32 + j * 8];        \
        _Pragma("unroll")                                                      \
        for (int e = 0; e < 8; ++e) {                                          \
          float hf = (float)hv[e];                                             \
          const float* wrow = &W8l[(wc * 64 + ch * 32 + j * 8 + e) * 10];      \
          _Pragma("unroll")                                                    \
          for (int c = 0; c < 10; ++c) p[c] += hf * wrow[c];                   \
        }                                                                      \
      }                                                                        \
      _Pragma("unroll")                                                        \
      for (int c = 0; c < 10; ++c) p[c] += __shfl_xor(p[c], 1);                \
      if (ch == 0) {                                                           \
        int row = bm + wr * 64 + (HALF) * 32 + lrr;                            \
        _Pragma("unroll")                                                      \
        for (int c = 0; c < 10; ++c) pout[(size_t)row * 10 + c] = p[c];        \
      }                                                                        \
    }                                                                          \
  } while (0)

    HEPI(0);
    HEPI(1);
#undef HEPI
    return;
  }

  // ---- epilogue: two wave-private half-passes, HALF is a LITERAL (rule #20) ----
  const int cbase = (lane & 1) * 4;            // chunk group 0..3 / 4..7

#define EPIHALF(HALF) do {                                                     \
    _Pragma("unroll")                                                          \
    for (int nf = 0; nf < 4; ++nf) {                                           \
      int colq = nf * 16 + rml;                                                \
      float bv = bias[bn + wc * 64 + colq];                                    \
      _Pragma("unroll")                                                        \
      for (int mfh = 0; mfh < 2; ++mfh) {                                      \
        _Pragma("unroll")                                                      \
        for (int r = 0; r < 4; ++r) {                                          \
          int lr = mfh * 16 + kq * 4 + r;                                      \
          float v = fmaxf(acc[(HALF) * 2 + mfh][nf][r] + bv, 0.0f) * invq;     \
          sm[eb + lr * 68 + colq] = (_Float16)v;                               \
        }                                                                      \
      }                                                                        \
    }                                                                          \
    LKW0();                                                                    \
    {                                                                          \
      int grow = bm + wr * 64 + (HALF) * 32 + lrr;                             \
      int col0 = bn + wc * 64;                                                 \
      uint64_t mw = 0;                                                         \
      if (DROP) mw = mask[(size_t)grow * 8 + (size_t)(col0 >> 6)];             \
      _Pragma("unroll")                                                        \
      for (int c = 0; c < 4; ++c) {                                            \
        int cc = cbase + c;                                                    \
        uint64_t lo = *(const uint64_t*)&sm[eb + lrr * 68 + cc * 8];           \
        uint64_t hi = *(const uint64_t*)&sm[eb + lrr * 68 + cc * 8 + 4];       \
        if (DROP) {                                                            \
          uint32_t bits = (uint32_t)(mw >> (cc * 8)) & 0xffu;                  \
          uint64_t klo = 0, khi = 0;                                           \
          if (bits & 0x01u) klo |= 0x000000000000ffffull;                      \
          if (bits & 0x02u) klo |= 0x00000000ffff0000ull;                      \
          if (bits & 0x04u) klo |= 0x0000ffff00000000ull;                      \
          if (bits & 0x08u) klo |= 0xffff000000000000ull;                      \
          if (bits & 0x10u) khi |= 0x000000000000ffffull;                      \
          if (bits & 0x20u) khi |= 0x00000000ffff0000ull;                      \
          if (bits & 0x40u) khi |= 0x0000ffff00000000ull;                      \
          if (bits & 0x80u) khi |= 0xffff000000000000ull;                      \
          lo &= klo; hi &= khi;                                                \
        }                                                                      \
        u64x2 ov; ov[0] = lo; ov[1] = hi;                                      \
        *(u64x2*)&C[(size_t)grow * 512 + col0 + cc * 8] = ov;                  \
      }                                                                        \
    }                                                                          \
  } while (0)

  EPIHALF(0);
  // same-wave DS ordering sequences half-1 ds_writes after half-0 ds_reads
  EPIHALF(1);
#undef EPIHALF
}

// ---- softmax over summed partial logits: out[row][c] ----
__global__ __launch_bounds__(256) void smax_k(const float* __restrict__ plog,
                                              const float* __restrict__ b8,
                                              float* __restrict__ out)
{
  int row = blockIdx.x * 256 + threadIdx.x;    // 65536 rows
  float l[10];
#pragma unroll
  for (int c = 0; c < 10; ++c) l[c] = b8[c];
#pragma unroll
  for (int s = 0; s < 8; ++s) {
    const float* pr = &plog[(size_t)s * 655360 + (size_t)row * 10];
#pragma unroll
    for (int c = 0; c < 10; ++c) l[c] += pr[c];
  }
  float mx = l[0];
#pragma unroll
  for (int c = 1; c < 10; ++c) mx = fmaxf(mx, l[c]);
  float sum = 0.f, e[10];
#pragma unroll
  for (int c = 0; c < 10; ++c) { e[c] = expf(l[c] - mx); sum += e[c]; }
  float is = 1.0f / sum;
#pragma unroll
  for (int c = 0; c < 10; ++c) out[(size_t)row * 10 + c] = e[c] * is;
}

extern "C" void kernel_launch(void* const* d_in, const int* in_sizes, int n_in,
                              void* d_out, int out_size, void* d_ws, size_t ws_size,
                              hipStream_t stream) {
  (void)in_sizes; (void)n_in; (void)out_size; (void)ws_size;
  const float* x = (const float*)d_in[0];
  const float* W[8]; const float* B[8];
  for (int i = 0; i < 8; ++i) { W[i] = (const float*)d_in[1 + 2*i]; B[i] = (const float*)d_in[2 + 2*i]; }

  char* w = (char*)d_ws;                       // ~260 MB total
  _Float16* xpad = (_Float16*)(w);             // 65536*832 fp16   = 109,051,904 B
  float*    plog = (float*)(w);                // 8 x 655360 f32 = 21 MB (reuses xpad,
                                               // dead after g1; g7 writes, smax reads)
  _Float16* hA   = (_Float16*)(w + 109051904); // 65536*512 fp16   =  67,108,864 B
  _Float16* hB   = (_Float16*)(w + 176160768); // 65536*512 fp16   =  67,108,864 B
  _Float16* WT1  = (_Float16*)(w + 243269632); // 512*832 fp16     =     851,968 B
  _Float16* WT   = (_Float16*)(w + 244121600); // 6 x 512*512 fp16 =   3,145,728 B
  unsigned long long* masks = (unsigned long long*)(w + 247267328); // 3*4 MiB
  unsigned long long* mL0 = masks;
  unsigned long long* mL1 = masks + 524288;
  unsigned long long* mL2 = masks + 1048576;

  // jax.random.split(key(42), 3), threefry_partitionable (foldlike) path:
  // child i = BOTH output words of threefry(key=(0,42), counter=(0,i))
  uint32_t d00,d01,d10,d11,d20,d21;
  tf2x32(0u, 42u, 0u, 0u, d00, d01);           // dk[0]  (p=0.2, q=0.8)
  tf2x32(0u, 42u, 0u, 1u, d10, d11);           // dk[1]  (p=0.3, q=0.7)
  tf2x32(0u, 42u, 0u, 2u, d20, d21);           // dk[2]  (p=0.5, q=0.5)

  cvt_x_f<<<26624, 256, 0, stream>>>(x, xpad, mL0, d00, d01);
  cvt_w_f<<<7810, 256, 0, stream>>>(W[0],W[1],W[2],W[3],W[4],W[5],W[6], WT1, WT,
                                    mL0, d00, d01);

  dim3 g(2048), b(256);
  // hosting: mL0 by cvt_x+cvt_w (used g2); mL1 by g2+g3 (used g4);
  // mL2 by g4+g5 (used g6). 8192 waves x 32 words = 262144 per host kernel.
  gemm_r<false,false><<<g, b, 0, stream>>>(xpad, WT1,           B[0], nullptr, 1.0f,      hA, 832,
                                     nullptr, 0u, 0, 0u, 0u, 0.f, nullptr, nullptr);
  gemm_r<true ,false><<<g, b, 0, stream>>>(hA,   WT + 0*262144, B[1], mL0,     1.0f/0.8f, hB, 512,
                                     mL1, 0u,       32, d10, d11, 0.7f, nullptr, nullptr);
  gemm_r<false,false><<<g, b, 0, stream>>>(hB,   WT + 1*262144, B[2], nullptr, 1.0f,      hA, 512,
                                     mL1, 262144u,  32, d10, d11, 0.7f, nullptr, nullptr);
  gemm_r<true ,false><<<g, b, 0, stream>>>(hA,   WT + 2*262144, B[3], mL1,     1.0f/0.7f, hB, 512,
                                     mL2, 0u,       32, d20, d21, 0.5f, nullptr, nullptr);
  gemm_r<false,false><<<g, b, 0, stream>>>(hB,   WT + 3*262144, B[4], nullptr, 1.0f,      hA, 512,
                                     mL2, 262144u,  32, d20, d21, 0.5f, nullptr, nullptr);
  gemm_r<true ,false><<<g, b, 0, stream>>>(hA,   WT + 4*262144, B[5], mL2,     2.0f,      hB, 512,
                                     nullptr, 0u, 0, 0u, 0u, 0.f, nullptr, nullptr);
  gemm_r<false,true ><<<g, b, 0, stream>>>(hB,   WT + 5*262144, B[6], nullptr, 1.0f,      hA, 512,
                                     nullptr, 0u, 0, 0u, 0u, 0.f, W[7], plog);
  smax_k<<<256, 256, 0, stream>>>(plog, B[7], (float*)d_out);
}